// Round 1
// baseline (283.288 us; speedup 1.0000x reference)
//
#include <hip/hip_runtime.h>
#include <math.h>

#define B_ 4
#define C_ 64
#define H_ 32
#define W_ 32
#define HW_ 1024
#define NH_ 8

// ---------------- K1: fused 1x1 convs (conv_out + qkv) ----------------
// grid: 4096 blocks = b(4) x ocb(64) x pt(16); 256 thr = 4 oc x 64 p
__global__ __launch_bounds__(256) void k_convs(
    const float* __restrict__ x, const float* __restrict__ w_conv, const float* __restrict__ b_conv,
    const float* __restrict__ w_qkv, const float* __restrict__ b_qkv,
    float* __restrict__ out, float* __restrict__ qws, float* __restrict__ kws, float* __restrict__ vws)
{
  int bid = blockIdx.x;
  int pt  = bid & 15;
  int ocb = (bid >> 4) & 63;
  int b   = bid >> 10;
  int lane = threadIdx.x & 63;
  int oc = ocb * 4 + (threadIdx.x >> 6);     // 0..255
  int p  = pt * 64 + lane;

  const float* xb = x + b * C_ * HW_ + p;
  const float* wrow;
  float acc;
  if (oc < 64) { wrow = w_conv + oc * 64; acc = b_conv[oc]; }
  else         { wrow = w_qkv + (oc - 64) * 64; acc = b_qkv[oc - 64]; }

  #pragma unroll 16
  for (int ci = 0; ci < 64; ++ci)
    acc = fmaf(wrow[ci], xb[ci * HW_], acc);

  if (oc < 64) {
    out[(b * 128 + oc) * HW_ + p] = acc;                       // conv_out channels 0..63
  } else {
    int qc = oc - 64;
    if (qc < 64) {                                             // q, scaled, channel-major
      qws[(b * 64 + qc) * HW_ + p] = acc * 0.35355339059327373f; // dkh^-0.5
    } else if (qc < 128) {                                     // k, position-major [p][8]
      int c = qc - 64; int n = c >> 3, d = c & 7;
      kws[((b * NH_ + n) * HW_ + p) * 8 + d] = acc;
    } else {                                                   // v, position-major [p][8]
      int c = qc - 128; int n = c >> 3, d = c & 7;
      vws[((b * NH_ + n) * HW_ + p) * 8 + d] = acc;
    }
  }
}

// ---------------- K2: attention with relative logits ----------------
// grid: 512 blocks = bn(32) x qtile(16); 256 thr = 64 queries x 4 key-chunks
__global__ __launch_bounds__(256) void k_attn(
    const float* __restrict__ qws, const float* __restrict__ kws, const float* __restrict__ vws,
    const float* __restrict__ rel_h, const float* __restrict__ rel_w,
    float* __restrict__ aws)
{
  int bid = blockIdx.x;
  int qt = bid & 15;
  int bn = bid >> 4;
  int b = bn >> 3, n = bn & 7;
  int ks = threadIdx.x & 3;        // key chunk: h' in [ks*8, ks*8+8)
  int qi = threadIdx.x >> 2;       // 0..63
  int p = qt * 64 + qi;
  int h = p >> 5, w = p & 31;

  float q[8];
  const float* qp = qws + (b * 64 + n * 8) * HW_ + p;
  #pragma unroll
  for (int d = 0; d < 8; ++d) q[d] = qp[d * HW_];

  const float* kbase = kws + (b * NH_ + n) * HW_ * 8;
  const float* vbase = vws + (b * NH_ + n) * HW_ * 8;

  float m = -1e30f, l = 0.f;
  float acc[8];
  #pragma unroll
  for (int d = 0; d < 8; ++d) acc[d] = 0.f;

  for (int hp = ks * 8; hp < ks * 8 + 8; ++hp) {
    const float4 rh0 = *(const float4*)(rel_h + (hp - h + 31) * 8);
    const float4 rh1 = *(const float4*)(rel_h + (hp - h + 31) * 8 + 4);
    float rh = q[0]*rh0.x + q[1]*rh0.y + q[2]*rh0.z + q[3]*rh0.w
             + q[4]*rh1.x + q[5]*rh1.y + q[6]*rh1.z + q[7]*rh1.w;
    int kk0 = hp * 32;
    for (int wp = 0; wp < 32; ++wp) {
      const float4 rw0 = *(const float4*)(rel_w + (wp - w + 31) * 8);
      const float4 rw1 = *(const float4*)(rel_w + (wp - w + 31) * 8 + 4);
      const float4 k0 = *(const float4*)(kbase + (kk0 + wp) * 8);
      const float4 k1 = *(const float4*)(kbase + (kk0 + wp) * 8 + 4);
      const float4 v0 = *(const float4*)(vbase + (kk0 + wp) * 8);
      const float4 v1 = *(const float4*)(vbase + (kk0 + wp) * 8 + 4);
      float s = rh;
      s = fmaf(q[0], k0.x + rw0.x, s);  // note: q·k + q·rw = q·(k+rw)
      s = fmaf(q[1], k0.y + rw0.y, s);
      s = fmaf(q[2], k0.z + rw0.z, s);
      s = fmaf(q[3], k0.w + rw0.w, s);
      s = fmaf(q[4], k1.x + rw1.x, s);
      s = fmaf(q[5], k1.y + rw1.y, s);
      s = fmaf(q[6], k1.z + rw1.z, s);
      s = fmaf(q[7], k1.w + rw1.w, s);
      float mn = fmaxf(m, s);
      float pe   = __expf(s - mn);
      float corr = __expf(m - mn);
      l = l * corr + pe;
      acc[0] = acc[0] * corr + pe * v0.x;
      acc[1] = acc[1] * corr + pe * v0.y;
      acc[2] = acc[2] * corr + pe * v0.z;
      acc[3] = acc[3] * corr + pe * v0.w;
      acc[4] = acc[4] * corr + pe * v1.x;
      acc[5] = acc[5] * corr + pe * v1.y;
      acc[6] = acc[6] * corr + pe * v1.z;
      acc[7] = acc[7] * corr + pe * v1.w;
      m = mn;
    }
  }

  // merge the 4 key-chunks (lanes qi*4+ks) via xor butterfly
  #pragma unroll
  for (int off = 1; off <= 2; off <<= 1) {
    float m2 = __shfl_xor(m, off);
    float l2 = __shfl_xor(l, off);
    float mn = fmaxf(m, m2);
    float ca = __expf(m - mn), cb = __expf(m2 - mn);
    l = l * ca + l2 * cb;
    #pragma unroll
    for (int d = 0; d < 8; ++d) {
      float a2 = __shfl_xor(acc[d], off);
      acc[d] = acc[d] * ca + a2 * cb;
    }
    m = mn;
  }

  if (ks == 0) {
    float inv = 1.f / l;
    float* ap = aws + (b * 64 + n * 8) * HW_ + p;
    #pragma unroll
    for (int d = 0; d < 8; ++d) ap[d * HW_] = acc[d] * inv;
  }
}

// ---------------- K3: 1x1 conv on attention map ----------------
// grid: 1024 blocks = b(4) x ocb(16) x pt(16); 256 thr = 4 co x 64 p
__global__ __launch_bounds__(256) void k_attnconv(
    const float* __restrict__ aws, const float* __restrict__ w_attn, const float* __restrict__ b_attn,
    float* __restrict__ out)
{
  int bid = blockIdx.x;
  int pt  = bid & 15;
  int ocb = (bid >> 4) & 15;
  int b   = bid >> 8;
  int lane = threadIdx.x & 63;
  int co = ocb * 4 + (threadIdx.x >> 6);   // 0..63
  int p  = pt * 64 + lane;

  const float* ab = aws + b * 64 * HW_ + p;
  const float* wrow = w_attn + co * 64;
  float acc = b_attn[co];
  #pragma unroll 16
  for (int ci = 0; ci < 64; ++ci)
    acc = fmaf(wrow[ci], ab[ci * HW_], acc);
  out[(b * 128 + 64 + co) * HW_ + p] = acc;
}

extern "C" void kernel_launch(void* const* d_in, const int* in_sizes, int n_in,
                              void* d_out, int out_size, void* d_ws, size_t ws_size,
                              hipStream_t stream) {
  const float* x        = (const float*)d_in[0];
  const float* w_conv   = (const float*)d_in[1];
  const float* b_conv   = (const float*)d_in[2];
  const float* w_qkv    = (const float*)d_in[3];
  const float* b_qkv    = (const float*)d_in[4];
  const float* w_attn   = (const float*)d_in[5];
  const float* b_attn   = (const float*)d_in[6];
  const float* rel_h    = (const float*)d_in[7];
  const float* rel_w    = (const float*)d_in[8];
  float* out = (float*)d_out;

  float* ws  = (float*)d_ws;
  float* qws = ws;               // [4][64][1024]
  float* kws = ws + 262144;      // [4][8][1024][8]
  float* vws = ws + 524288;      // [4][8][1024][8]
  float* aws = ws + 786432;      // [4][64][1024]

  k_convs<<<4096, 256, 0, stream>>>(x, w_conv, b_conv, w_qkv, b_qkv, out, qws, kws, vws);
  k_attn<<<512, 256, 0, stream>>>(qws, kws, vws, rel_h, rel_w, aws);
  k_attnconv<<<1024, 256, 0, stream>>>(aws, w_attn, b_attn, out);
}

// Round 2
// 263.766 us; speedup vs baseline: 1.0740x; 1.0740x over previous
//
#include <hip/hip_runtime.h>
#include <math.h>

#define B_ 4
#define C_ 64
#define H_ 32
#define W_ 32
#define HW_ 1024
#define NH_ 8

// ---------------- K1: fused 1x1 convs (conv_out + qkv) ----------------
// grid: 4096 blocks = b(4) x ocb(64) x pt(16); 256 thr = 4 oc x 64 p
__global__ __launch_bounds__(256) void k_convs(
    const float* __restrict__ x, const float* __restrict__ w_conv, const float* __restrict__ b_conv,
    const float* __restrict__ w_qkv, const float* __restrict__ b_qkv,
    float* __restrict__ out, float* __restrict__ qws, float* __restrict__ kws, float* __restrict__ vws)
{
  int bid = blockIdx.x;
  int pt  = bid & 15;
  int ocb = (bid >> 4) & 63;
  int b   = bid >> 10;
  int lane = threadIdx.x & 63;
  int oc = ocb * 4 + (threadIdx.x >> 6);     // 0..255
  int p  = pt * 64 + lane;

  const float* xb = x + b * C_ * HW_ + p;
  const float* wrow;
  float acc;
  if (oc < 64) { wrow = w_conv + oc * 64; acc = b_conv[oc]; }
  else         { wrow = w_qkv + (oc - 64) * 64; acc = b_qkv[oc - 64]; }

  #pragma unroll 16
  for (int ci = 0; ci < 64; ++ci)
    acc = fmaf(wrow[ci], xb[ci * HW_], acc);

  if (oc < 64) {
    out[(b * 128 + oc) * HW_ + p] = acc;                       // conv_out channels 0..63
  } else {
    int qc = oc - 64;
    if (qc < 64) {                                             // q, scaled, channel-major
      qws[(b * 64 + qc) * HW_ + p] = acc * 0.35355339059327373f; // dkh^-0.5
    } else if (qc < 128) {                                     // k, position-major [p][8]
      int c = qc - 64; int n = c >> 3, d = c & 7;
      kws[((b * NH_ + n) * HW_ + p) * 8 + d] = acc;
    } else {                                                   // v, position-major [p][8]
      int c = qc - 128; int n = c >> 3, d = c & 7;
      vws[((b * NH_ + n) * HW_ + p) * 8 + d] = acc;
    }
  }
}

// ---------------- K2: attention with relative logits ----------------
// grid: 1024 blocks = bn(32) x qtile(32); 256 thr = 32 queries x 8 key-chunks
// Chunked online softmax: one rescale per 32-key row instead of per key.
__global__ __launch_bounds__(256, 4) void k_attn(
    const float* __restrict__ qws, const float* __restrict__ kws, const float* __restrict__ vws,
    const float* __restrict__ rel_h, const float* __restrict__ rel_w,
    float* __restrict__ aws)
{
  int bid = blockIdx.x;
  int qt = bid & 31;
  int bn = bid >> 5;
  int b = bn >> 3, n = bn & 7;
  int tid = threadIdx.x;
  int ks = tid & 7;                // key chunk: h' in [ks*4, ks*4+4)
  int qi = tid >> 3;               // 0..31
  int p = qt * 32 + qi;
  int h = p >> 5, w = p & 31;

  float q[8];
  const float* qp = qws + (b * 64 + n * 8) * HW_ + p;
  #pragma unroll
  for (int d = 0; d < 8; ++d) q[d] = qp[d * HW_];

  // hoist q . rel_w[wp - w + 31] for all 32 wp (reused by every key-row)
  float rwd[32];
  #pragma unroll
  for (int wp = 0; wp < 32; ++wp) {
    const float4 a0 = *(const float4*)(rel_w + (wp - w + 31) * 8);
    const float4 a1 = *(const float4*)(rel_w + (wp - w + 31) * 8 + 4);
    rwd[wp] = q[0]*a0.x + q[1]*a0.y + q[2]*a0.z + q[3]*a0.w
            + q[4]*a1.x + q[5]*a1.y + q[6]*a1.z + q[7]*a1.w;
  }

  const float* kbase = kws + (b * NH_ + n) * HW_ * 8;
  const float* vbase = vws + (b * NH_ + n) * HW_ * 8;

  float m = -1e30f, l = 0.f;
  float acc[8];
  #pragma unroll
  for (int d = 0; d < 8; ++d) acc[d] = 0.f;

  for (int r = 0; r < 4; ++r) {
    int hp = ks * 4 + r;
    const float4 b0 = *(const float4*)(rel_h + (hp - h + 31) * 8);
    const float4 b1 = *(const float4*)(rel_h + (hp - h + 31) * 8 + 4);
    float rh = q[0]*b0.x + q[1]*b0.y + q[2]*b0.z + q[3]*b0.w
             + q[4]*b1.x + q[5]*b1.y + q[6]*b1.z + q[7]*b1.w;

    // 32 independent scores
    float s[32];
    const float* krow = kbase + hp * 32 * 8;
    #pragma unroll
    for (int wp = 0; wp < 32; ++wp) {
      const float4 k0 = *(const float4*)(krow + wp * 8);
      const float4 k1 = *(const float4*)(krow + wp * 8 + 4);
      float t = rh + rwd[wp];
      t = fmaf(q[0], k0.x, t);
      t = fmaf(q[1], k0.y, t);
      t = fmaf(q[2], k0.z, t);
      t = fmaf(q[3], k0.w, t);
      t = fmaf(q[4], k1.x, t);
      t = fmaf(q[5], k1.y, t);
      t = fmaf(q[6], k1.z, t);
      t = fmaf(q[7], k1.w, t);
      s[wp] = t;
    }

    // tree max of chunk
    float t16[16];
    #pragma unroll
    for (int i = 0; i < 16; ++i) t16[i] = fmaxf(s[i], s[i + 16]);
    #pragma unroll
    for (int st = 8; st >= 1; st >>= 1)
      #pragma unroll
      for (int i = 0; i < 8; ++i)
        if (i < st) t16[i] = fmaxf(t16[i], t16[i + st]);
    float mn = fmaxf(m, t16[0]);
    float corr = __expf(m - mn);
    m = mn;

    // independent exps
    #pragma unroll
    for (int wp = 0; wp < 32; ++wp) s[wp] = __expf(s[wp] - mn);

    // tree sum for l
    float u16[16];
    #pragma unroll
    for (int i = 0; i < 16; ++i) u16[i] = s[i] + s[i + 16];
    #pragma unroll
    for (int st = 8; st >= 1; st >>= 1)
      #pragma unroll
      for (int i = 0; i < 8; ++i)
        if (i < st) u16[i] = u16[i] + u16[i + st];
    l = fmaf(l, corr, u16[0]);

    // rescale once, then 8 independent FMA chains into acc
    #pragma unroll
    for (int d = 0; d < 8; ++d) acc[d] *= corr;
    const float* vrow = vbase + hp * 32 * 8;
    #pragma unroll
    for (int wp = 0; wp < 32; ++wp) {
      const float4 v0 = *(const float4*)(vrow + wp * 8);
      const float4 v1 = *(const float4*)(vrow + wp * 8 + 4);
      float pe = s[wp];
      acc[0] = fmaf(pe, v0.x, acc[0]);
      acc[1] = fmaf(pe, v0.y, acc[1]);
      acc[2] = fmaf(pe, v0.z, acc[2]);
      acc[3] = fmaf(pe, v0.w, acc[3]);
      acc[4] = fmaf(pe, v1.x, acc[4]);
      acc[5] = fmaf(pe, v1.y, acc[5]);
      acc[6] = fmaf(pe, v1.z, acc[6]);
      acc[7] = fmaf(pe, v1.w, acc[7]);
    }
  }

  // merge the 8 key-chunks (lane = qi*8+ks) via xor butterfly
  #pragma unroll
  for (int off = 1; off <= 4; off <<= 1) {
    float m2 = __shfl_xor(m, off);
    float l2 = __shfl_xor(l, off);
    float mn = fmaxf(m, m2);
    float ca = __expf(m - mn), cb = __expf(m2 - mn);
    l = l * ca + l2 * cb;
    #pragma unroll
    for (int d = 0; d < 8; ++d) {
      float a2 = __shfl_xor(acc[d], off);
      acc[d] = acc[d] * ca + a2 * cb;
    }
    m = mn;
  }

  if (ks == 0) {
    float inv = 1.f / l;
    float* ap = aws + (b * 64 + n * 8) * HW_ + p;
    #pragma unroll
    for (int d = 0; d < 8; ++d) ap[d * HW_] = acc[d] * inv;
  }
}

// ---------------- K3: 1x1 conv on attention map ----------------
// grid: 1024 blocks = b(4) x ocb(16) x pt(16); 256 thr = 4 co x 64 p
__global__ __launch_bounds__(256) void k_attnconv(
    const float* __restrict__ aws, const float* __restrict__ w_attn, const float* __restrict__ b_attn,
    float* __restrict__ out)
{
  int bid = blockIdx.x;
  int pt  = bid & 15;
  int ocb = (bid >> 4) & 15;
  int b   = bid >> 8;
  int lane = threadIdx.x & 63;
  int co = ocb * 4 + (threadIdx.x >> 6);   // 0..63
  int p  = pt * 64 + lane;

  const float* ab = aws + b * 64 * HW_ + p;
  const float* wrow = w_attn + co * 64;
  float acc = b_attn[co];
  #pragma unroll 16
  for (int ci = 0; ci < 64; ++ci)
    acc = fmaf(wrow[ci], ab[ci * HW_], acc);
  out[(b * 128 + 64 + co) * HW_ + p] = acc;
}

extern "C" void kernel_launch(void* const* d_in, const int* in_sizes, int n_in,
                              void* d_out, int out_size, void* d_ws, size_t ws_size,
                              hipStream_t stream) {
  const float* x        = (const float*)d_in[0];
  const float* w_conv   = (const float*)d_in[1];
  const float* b_conv   = (const float*)d_in[2];
  const float* w_qkv    = (const float*)d_in[3];
  const float* b_qkv    = (const float*)d_in[4];
  const float* w_attn   = (const float*)d_in[5];
  const float* b_attn   = (const float*)d_in[6];
  const float* rel_h    = (const float*)d_in[7];
  const float* rel_w    = (const float*)d_in[8];
  float* out = (float*)d_out;

  float* ws  = (float*)d_ws;
  float* qws = ws;               // [4][64][1024]
  float* kws = ws + 262144;      // [4][8][1024][8]
  float* vws = ws + 524288;      // [4][8][1024][8]
  float* aws = ws + 786432;      // [4][64][1024]

  k_convs<<<4096, 256, 0, stream>>>(x, w_conv, b_conv, w_qkv, b_qkv, out, qws, kws, vws);
  k_attn<<<1024, 256, 0, stream>>>(qws, kws, vws, rel_h, rel_w, aws);
  k_attnconv<<<1024, 256, 0, stream>>>(aws, w_attn, b_attn, out);
}

// Round 3
// 75.947 us; speedup vs baseline: 3.7301x; 3.4730x over previous
//
#include <hip/hip_runtime.h>
#include <math.h>

#define B_ 4
#define C_ 64
#define HW_ 1024
#define NH_ 8

// ---------------- K1: fused 1x1 convs (conv_out + qkv) ----------------
// grid: 4096 blocks = b(4) x ocb(64) x pt(16); 256 thr = 4 oc x 64 p
__global__ __launch_bounds__(256) void k_convs(
    const float* __restrict__ x, const float* __restrict__ w_conv, const float* __restrict__ b_conv,
    const float* __restrict__ w_qkv, const float* __restrict__ b_qkv,
    float* __restrict__ out, float* __restrict__ qws, float* __restrict__ kws, float* __restrict__ vws)
{
  int bid = blockIdx.x;
  int pt  = bid & 15;
  int ocb = (bid >> 4) & 63;
  int b   = bid >> 10;
  int lane = threadIdx.x & 63;
  int oc = ocb * 4 + (threadIdx.x >> 6);     // 0..255
  int p  = pt * 64 + lane;

  const float* xb = x + b * C_ * HW_ + p;
  const float* wrow;
  float acc;
  if (oc < 64) { wrow = w_conv + oc * 64; acc = b_conv[oc]; }
  else         { wrow = w_qkv + (oc - 64) * 64; acc = b_qkv[oc - 64]; }

  #pragma unroll 16
  for (int ci = 0; ci < 64; ++ci)
    acc = fmaf(wrow[ci], xb[ci * HW_], acc);

  if (oc < 64) {
    out[(b * 128 + oc) * HW_ + p] = acc;                       // conv_out channels 0..63
  } else {
    int qc = oc - 64;
    if (qc < 64) {                                             // q, scaled, channel-major
      qws[(b * 64 + qc) * HW_ + p] = acc * 0.35355339059327373f; // dkh^-0.5
    } else if (qc < 128) {                                     // k, position-major [p][8]
      int c = qc - 64; int n = c >> 3, d = c & 7;
      kws[((b * NH_ + n) * HW_ + p) * 8 + d] = acc;
    } else {                                                   // v, position-major [p][8]
      int c = qc - 128; int n = c >> 3, d = c & 7;
      vws[((b * NH_ + n) * HW_ + p) * 8 + d] = acc;
    }
  }
}

// ---------------- K2: attention, LDS-resident K/V, 4 queries/thread ----------------
// grid: 512 blocks = bn(32) x qt(16); block = 64 q-rows x 1024 keys
// thread (qg=tid>>4, kc=tid&15): 4 q-rows (qg*4+i), 64 keys (kc*64 + j)
__global__ __launch_bounds__(256, 2) void k_attn(
    const float* __restrict__ qws, const float* __restrict__ kws, const float* __restrict__ vws,
    const float* __restrict__ rel_h, const float* __restrict__ rel_w,
    float* __restrict__ aws)
{
  __shared__ float4 kls[2048];      // 1024 keys x 2 halves, XOR-swizzled (32KB)
  __shared__ float4 vls[2048];      // (32KB)
  __shared__ float  rwd[64 * 36];   // rwd[q][wp], row-padded to 36 (9.2KB)

  int bid = blockIdx.x;
  int qt = bid & 15;
  int bn = bid >> 4;
  int b = bn >> 3, n = bn & 7;
  int tid = threadIdx.x;
  int kc = tid & 15, qg = tid >> 4;

  // ---- stage K,V into LDS (swizzled: unit u = gidx ^ (((gidx>>7)&7)<<1)) ----
  const float4* kg = (const float4*)(kws + (size_t)bn * (HW_ * 8));
  const float4* vg = (const float4*)(vws + (size_t)bn * (HW_ * 8));
  #pragma unroll
  for (int s = 0; s < 8; ++s) {
    int gidx = tid * 8 + s;                       // = kk*2 + dh
    int u = gidx ^ (((gidx >> 7) & 7) << 1);      // spread by kk>>6 (key-chunk)
    kls[u] = kg[gidx];
    vls[u] = vg[gidx];
  }

  // ---- cooperative rwd table: rwd[q][wp] = q_q . rel_w[wp - w(q) + 31] ----
  {
    int qr = tid >> 2, w4 = tid & 3;              // q-row 0..63, wp-quarter 0..3
    float qv[8];
    const float* qp = qws + (b * 64 + n * 8) * HW_ + qt * 64 + qr;
    #pragma unroll
    for (int d = 0; d < 8; ++d) qv[d] = qp[d * HW_];
    int w = qr & 31;
    #pragma unroll
    for (int s = 0; s < 8; ++s) {
      int wp = w4 * 8 + s;
      const float4 r0 = *(const float4*)(rel_w + (wp - w + 31) * 8);
      const float4 r1 = *(const float4*)(rel_w + (wp - w + 31) * 8 + 4);
      rwd[qr * 36 + wp] =
          qv[0]*r0.x + qv[1]*r0.y + qv[2]*r0.z + qv[3]*r0.w
        + qv[4]*r1.x + qv[5]*r1.y + qv[6]*r1.z + qv[7]*r1.w;
    }
  }

  // ---- per-thread q rows + rhd (hp = kc*2 + hh is thread-constant) ----
  float q[4][8];
  float rhd0[4], rhd1[4];
  const float* qbase = qws + (b * 64 + n * 8) * HW_ + qt * 64;
  #pragma unroll
  for (int i = 0; i < 4; ++i) {
    int qrow = qg * 4 + i;
    #pragma unroll
    for (int d = 0; d < 8; ++d) q[i][d] = qbase[d * HW_ + qrow];
    int h = (qt * 64 + qrow) >> 5;
    const float* rp0 = rel_h + (kc * 2     - h + 31) * 8;
    const float* rp1 = rel_h + (kc * 2 + 1 - h + 31) * 8;
    float a0 = 0.f, a1 = 0.f;
    #pragma unroll
    for (int d = 0; d < 8; ++d) { a0 = fmaf(q[i][d], rp0[d], a0); a1 = fmaf(q[i][d], rp1[d], a1); }
    rhd0[i] = a0; rhd1[i] = a1;
  }

  __syncthreads();

  float m_[4], l_[4];
  float4 accA[4], accB[4];
  #pragma unroll
  for (int i = 0; i < 4; ++i) {
    m_[i] = -1e30f; l_[i] = 0.f;
    accA[i] = make_float4(0.f, 0.f, 0.f, 0.f);
    accB[i] = make_float4(0.f, 0.f, 0.f, 0.f);
  }

  int xorv = (kc & 7) << 1;

  #pragma unroll
  for (int hh = 0; hh < 2; ++hh) {
    #pragma unroll
    for (int cc = 0; cc < 4; ++cc) {
      int kk0 = kc * 64 + hh * 32 + cc * 8;

      // K fragments for 8 keys
      float4 kA[8], kB[8];
      #pragma unroll
      for (int k = 0; k < 8; ++k) {
        int u = ((kk0 + k) << 1) ^ xorv;
        kA[k] = kls[u]; kB[k] = kls[u + 1];
      }
      // rel_w values (wp = cc*8 .. +7) for the 4 q rows
      float rw8[4][8];
      #pragma unroll
      for (int i = 0; i < 4; ++i) {
        const float* rp = &rwd[(qg * 4 + i) * 36 + cc * 8];
        float4 ra = *(const float4*)rp, rb = *(const float4*)(rp + 4);
        rw8[i][0]=ra.x; rw8[i][1]=ra.y; rw8[i][2]=ra.z; rw8[i][3]=ra.w;
        rw8[i][4]=rb.x; rw8[i][5]=rb.y; rw8[i][6]=rb.z; rw8[i][7]=rb.w;
      }

      // scores
      float s[4][8];
      #pragma unroll
      for (int i = 0; i < 4; ++i) {
        float rh = hh ? rhd1[i] : rhd0[i];
        #pragma unroll
        for (int k = 0; k < 8; ++k) {
          float t = rh + rw8[i][k];
          t = fmaf(q[i][0], kA[k].x, t);
          t = fmaf(q[i][1], kA[k].y, t);
          t = fmaf(q[i][2], kA[k].z, t);
          t = fmaf(q[i][3], kA[k].w, t);
          t = fmaf(q[i][4], kB[k].x, t);
          t = fmaf(q[i][5], kB[k].y, t);
          t = fmaf(q[i][6], kB[k].z, t);
          t = fmaf(q[i][7], kB[k].w, t);
          s[i][k] = t;
        }
      }

      // online softmax (chunk of 8), exps stored back into s
      #pragma unroll
      for (int i = 0; i < 4; ++i) {
        float c01 = fmaxf(s[i][0], s[i][1]);
        float c23 = fmaxf(s[i][2], s[i][3]);
        float c45 = fmaxf(s[i][4], s[i][5]);
        float c67 = fmaxf(s[i][6], s[i][7]);
        float cm = fmaxf(fmaxf(c01, c23), fmaxf(c45, c67));
        float mn = fmaxf(m_[i], cm);
        float corr = __expf(m_[i] - mn);
        m_[i] = mn;
        #pragma unroll
        for (int k = 0; k < 8; ++k) s[i][k] = __expf(s[i][k] - mn);
        float sm = ((s[i][0] + s[i][1]) + (s[i][2] + s[i][3]))
                 + ((s[i][4] + s[i][5]) + (s[i][6] + s[i][7]));
        l_[i] = fmaf(l_[i], corr, sm);
        accA[i].x *= corr; accA[i].y *= corr; accA[i].z *= corr; accA[i].w *= corr;
        accB[i].x *= corr; accB[i].y *= corr; accB[i].z *= corr; accB[i].w *= corr;
      }

      // V fragments + PV
      float4 vA[8], vB[8];
      #pragma unroll
      for (int k = 0; k < 8; ++k) {
        int u = ((kk0 + k) << 1) ^ xorv;
        vA[k] = vls[u]; vB[k] = vls[u + 1];
      }
      #pragma unroll
      for (int i = 0; i < 4; ++i) {
        #pragma unroll
        for (int k = 0; k < 8; ++k) {
          float e = s[i][k];
          accA[i].x = fmaf(e, vA[k].x, accA[i].x);
          accA[i].y = fmaf(e, vA[k].y, accA[i].y);
          accA[i].z = fmaf(e, vA[k].z, accA[i].z);
          accA[i].w = fmaf(e, vA[k].w, accA[i].w);
          accB[i].x = fmaf(e, vB[k].x, accB[i].x);
          accB[i].y = fmaf(e, vB[k].y, accB[i].y);
          accB[i].z = fmaf(e, vB[k].z, accB[i].z);
          accB[i].w = fmaf(e, vB[k].w, accB[i].w);
        }
      }
    }
  }

  // ---- merge the 16 kc-partials (in-wave butterfly over lane bits 0..3) ----
  #pragma unroll
  for (int off = 1; off <= 8; off <<= 1) {
    #pragma unroll
    for (int i = 0; i < 4; ++i) {
      float m2 = __shfl_xor(m_[i], off);
      float l2 = __shfl_xor(l_[i], off);
      float mn = fmaxf(m_[i], m2);
      float ca = __expf(m_[i] - mn), cb = __expf(m2 - mn);
      l_[i] = l_[i] * ca + l2 * cb;
      m_[i] = mn;
      float t;
      t = __shfl_xor(accA[i].x, off); accA[i].x = accA[i].x * ca + t * cb;
      t = __shfl_xor(accA[i].y, off); accA[i].y = accA[i].y * ca + t * cb;
      t = __shfl_xor(accA[i].z, off); accA[i].z = accA[i].z * ca + t * cb;
      t = __shfl_xor(accA[i].w, off); accA[i].w = accA[i].w * ca + t * cb;
      t = __shfl_xor(accB[i].x, off); accB[i].x = accB[i].x * ca + t * cb;
      t = __shfl_xor(accB[i].y, off); accB[i].y = accB[i].y * ca + t * cb;
      t = __shfl_xor(accB[i].z, off); accB[i].z = accB[i].z * ca + t * cb;
      t = __shfl_xor(accB[i].w, off); accB[i].w = accB[i].w * ca + t * cb;
    }
  }

  if (kc == 0) {
    float* ab = aws + (b * 64 + n * 8) * HW_ + qt * 64;
    #pragma unroll
    for (int i = 0; i < 4; ++i) {
      int qrow = qg * 4 + i;
      float inv = 1.f / l_[i];
      ab[0 * HW_ + qrow] = accA[i].x * inv;
      ab[1 * HW_ + qrow] = accA[i].y * inv;
      ab[2 * HW_ + qrow] = accA[i].z * inv;
      ab[3 * HW_ + qrow] = accA[i].w * inv;
      ab[4 * HW_ + qrow] = accB[i].x * inv;
      ab[5 * HW_ + qrow] = accB[i].y * inv;
      ab[6 * HW_ + qrow] = accB[i].z * inv;
      ab[7 * HW_ + qrow] = accB[i].w * inv;
    }
  }
}

// ---------------- K3: 1x1 conv on attention map ----------------
__global__ __launch_bounds__(256) void k_attnconv(
    const float* __restrict__ aws, const float* __restrict__ w_attn, const float* __restrict__ b_attn,
    float* __restrict__ out)
{
  int bid = blockIdx.x;
  int pt  = bid & 15;
  int ocb = (bid >> 4) & 15;
  int b   = bid >> 8;
  int lane = threadIdx.x & 63;
  int co = ocb * 4 + (threadIdx.x >> 6);   // 0..63
  int p  = pt * 64 + lane;

  const float* ab = aws + b * 64 * HW_ + p;
  const float* wrow = w_attn + co * 64;
  float acc = b_attn[co];
  #pragma unroll 16
  for (int ci = 0; ci < 64; ++ci)
    acc = fmaf(wrow[ci], ab[ci * HW_], acc);
  out[(b * 128 + 64 + co) * HW_ + p] = acc;
}

extern "C" void kernel_launch(void* const* d_in, const int* in_sizes, int n_in,
                              void* d_out, int out_size, void* d_ws, size_t ws_size,
                              hipStream_t stream) {
  const float* x        = (const float*)d_in[0];
  const float* w_conv   = (const float*)d_in[1];
  const float* b_conv   = (const float*)d_in[2];
  const float* w_qkv    = (const float*)d_in[3];
  const float* b_qkv    = (const float*)d_in[4];
  const float* w_attn   = (const float*)d_in[5];
  const float* b_attn   = (const float*)d_in[6];
  const float* rel_h    = (const float*)d_in[7];
  const float* rel_w    = (const float*)d_in[8];
  float* out = (float*)d_out;

  float* ws  = (float*)d_ws;
  float* qws = ws;               // [4][64][1024]
  float* kws = ws + 262144;      // [4][8][1024][8]
  float* vws = ws + 524288;      // [4][8][1024][8]
  float* aws = ws + 786432;      // [4][64][1024]

  k_convs<<<4096, 256, 0, stream>>>(x, w_conv, b_conv, w_qkv, b_qkv, out, qws, kws, vws);
  k_attn<<<512, 256, 0, stream>>>(qws, kws, vws, rel_h, rel_w, aws);
  k_attnconv<<<1024, 256, 0, stream>>>(aws, w_attn, b_attn, out);
}

// Round 5
// 68.389 us; speedup vs baseline: 4.1423x; 1.1105x over previous
//
#include <hip/hip_runtime.h>
#include <math.h>

#define HW_ 1024

typedef __attribute__((ext_vector_type(4))) float   f32x4;
typedef __attribute__((ext_vector_type(8))) short   s16x8;

__device__ __forceinline__ unsigned bf16rne(float x) {
  unsigned u = __builtin_bit_cast(unsigned, x);
  u += 0x7FFF + ((u >> 16) & 1);
  return u >> 16;
}

// ---------------- K1: fused 1x1 convs (conv_out + q/k/v staging, bf16 hi/lo) ----------------
// grid 1024 = b(4) x ocq(64) x pt(4); 256 thr = 4 oc x 64 p-quads
__global__ __launch_bounds__(256) void k_convs(
    const float* __restrict__ x, const float* __restrict__ w_conv, const float* __restrict__ b_conv,
    const float* __restrict__ w_qkv, const float* __restrict__ b_qkv,
    float* __restrict__ out,
    ushort* __restrict__ qh, ushort* __restrict__ ql,
    ushort* __restrict__ kh, ushort* __restrict__ kl,
    ushort* __restrict__ vtg)
{
  int bid = blockIdx.x;
  int pt  = bid & 3;
  int ocq = (bid >> 2) & 63;
  int b   = bid >> 8;
  int tid = threadIdx.x;
  int oc  = ocq * 4 + (tid >> 6);          // 0..255 (wave-uniform)
  int p   = pt * 256 + (tid & 63) * 4;

  const float* wrow;
  float bias;
  if (oc < 64) { wrow = w_conv + oc * 64; bias = b_conv[oc]; }
  else         { wrow = w_qkv + (oc - 64) * 64; bias = b_qkv[oc - 64]; }

  float4 acc = make_float4(bias, bias, bias, bias);
  const float* xb = x + (size_t)b * 64 * HW_ + p;
  #pragma unroll 16
  for (int ci = 0; ci < 64; ++ci) {
    float wv = wrow[ci];
    float4 x4 = *(const float4*)(xb + (size_t)ci * HW_);
    acc.x = fmaf(wv, x4.x, acc.x);
    acc.y = fmaf(wv, x4.y, acc.y);
    acc.z = fmaf(wv, x4.z, acc.z);
    acc.w = fmaf(wv, x4.w, acc.w);
  }

  float av[4] = {acc.x, acc.y, acc.z, acc.w};
  if (oc < 64) {
    *(float4*)(out + ((size_t)b * 128 + oc) * HW_ + p) = acc;
  } else if (oc < 128) {
    // q: scale by dkh^-0.5 * log2(e) (exp2 domain), split hi/lo bf16, layout [bn][p][8]
    const float SC = 0.35355339059327373f * 1.4426950408889634f;
    int qc = oc - 64, n = qc >> 3, d = qc & 7, bn = b * 8 + n;
    #pragma unroll
    for (int i = 0; i < 4; ++i) {
      float a = av[i] * SC;
      unsigned hb = bf16rne(a);
      float hf = __builtin_bit_cast(float, hb << 16);
      size_t idx = ((size_t)bn * HW_ + p + i) * 8 + d;
      qh[idx] = (ushort)hb;
      ql[idx] = (ushort)bf16rne(a - hf);
    }
  } else if (oc < 192) {
    int kc = oc - 128, n = kc >> 3, d = kc & 7, bn = b * 8 + n;
    #pragma unroll
    for (int i = 0; i < 4; ++i) {
      float a = av[i];
      unsigned hb = bf16rne(a);
      float hf = __builtin_bit_cast(float, hb << 16);
      size_t idx = ((size_t)bn * HW_ + p + i) * 8 + d;
      kh[idx] = (ushort)hb;
      kl[idx] = (ushort)bf16rne(a - hf);
    }
  } else {
    // v transposed: [bn][d][p]
    int vc = oc - 192, n = vc >> 3, d = vc & 7, bn = b * 8 + n;
    #pragma unroll
    for (int i = 0; i < 4; ++i)
      vtg[((size_t)bn * 8 + d) * HW_ + p + i] = (ushort)bf16rne(av[i]);
  }
}

// ---------------- K2: MFMA flash attention with relative logits ----------------
// grid 512 = bn(32) x qt(16); 4 waves, wave = 16 q-cols x 1024 keys
// S^T = mfma chain(K_hi/lo, Q^T_hi/lo, C=rel) -> lane: col q=l&15, key row=(l>>4)*4+reg
// P redistributed via per-wave LDS buffer (explicit [q][key] indexing)
// O^T = mfma(V^T, P^T, O)
__global__ __launch_bounds__(256, 2) void k_attn(
    const ushort* __restrict__ qhb, const ushort* __restrict__ qlb,
    const ushort* __restrict__ khb, const ushort* __restrict__ klb,
    const ushort* __restrict__ vtg,
    const float* __restrict__ rel_h, const float* __restrict__ rel_w,
    float* __restrict__ aws)
{
  __shared__ float rhd[64 * 33];
  __shared__ float rwd[64 * 33];
  __shared__ ushort P_lds[4][16][144];   // [wave][q][key], 144-pad: rows 16B-aligned

  int bid = blockIdx.x;
  int qt = bid & 15;
  int bn = bid >> 4;
  int b = bn >> 3, n = bn & 7;
  int tid = threadIdx.x;
  int lane = tid & 63;
  int wid = tid >> 6;

  // ---- build rel tables (f32, from hi+lo q): rhd[qr][hp], rwd[qr][wp]
  {
    int qr = tid >> 2, qu = tid & 3;
    const ushort* qph = qhb + ((size_t)bn * HW_ + qt * 64 + qr) * 8;
    const ushort* qpl = qlb + ((size_t)bn * HW_ + qt * 64 + qr) * 8;
    float qf[8];
    #pragma unroll
    for (int d = 0; d < 8; ++d)
      qf[d] = __builtin_bit_cast(float, (unsigned)qph[d] << 16)
            + __builtin_bit_cast(float, (unsigned)qpl[d] << 16);
    int h = (qt * 64 + qr) >> 5, w = qr & 31;
    #pragma unroll
    for (int s = 0; s < 8; ++s) {
      int idx = qu * 8 + s;                       // hp and wp
      const float* rp = rel_h + (idx - h + 31) * 8;
      float a = 0.f;
      #pragma unroll
      for (int d = 0; d < 8; ++d) a = fmaf(qf[d], rp[d], a);
      rhd[qr * 33 + idx] = a;
      const float* rq = rel_w + (idx - w + 31) * 8;
      float c = 0.f;
      #pragma unroll
      for (int d = 0; d < 8; ++d) c = fmaf(qf[d], rq[d], c);
      rwd[qr * 33 + idx] = c;
    }
  }
  __syncthreads();

  int q = lane & 15, g = lane >> 4;
  int qr = wid * 16 + q;                          // q row within block tile

  // Q^T B-frags (constant): lanes 0-15 hold Q[q][0..8]
  s16x8 qfh = {0,0,0,0,0,0,0,0}, qfl = {0,0,0,0,0,0,0,0};
  if (lane < 16) {
    size_t off = ((size_t)bn * HW_ + qt * 64 + wid * 16 + lane) * 8;
    qfh = *(const s16x8*)(qhb + off);
    qfl = *(const s16x8*)(qlb + off);
  }

  // hoisted rwd: wp = (t&1)*16 + g*4 + r
  float rw2[2][4];
  #pragma unroll
  for (int r = 0; r < 4; ++r) {
    rw2[0][r] = rwd[qr * 33 + g * 4 + r];
    rw2[1][r] = rwd[qr * 33 + 16 + g * 4 + r];
  }

  const ushort* khbase = khb + (size_t)bn * HW_ * 8;
  const ushort* klbase = klb + (size_t)bn * HW_ * 8;
  const ushort* vbase  = vtg + (size_t)bn * 8 * HW_;

  float m = -1e30f, lr = 0.f;
  f32x4 O = {0.f, 0.f, 0.f, 0.f};

  for (int bk = 0; bk < 8; ++bk) {
    float rh4[4];
    #pragma unroll
    for (int j = 0; j < 4; ++j) rh4[j] = rhd[qr * 33 + bk * 4 + j];

    // ---- QK^T (S^T), rel logits as C-init, hi/lo split (3 MFMAs)
    f32x4 s[8];
    #pragma unroll
    for (int t = 0; t < 8; ++t) {
      f32x4 c;
      #pragma unroll
      for (int r = 0; r < 4; ++r) c[r] = rh4[t >> 1] + rw2[t & 1][r];
      s16x8 kfh = {0,0,0,0,0,0,0,0}, kfl = {0,0,0,0,0,0,0,0};
      if (lane < 16) {
        size_t koff = (size_t)(bk * 128 + t * 16 + lane) * 8;
        kfh = *(const s16x8*)(khbase + koff);
        kfl = *(const s16x8*)(klbase + koff);
      }
      c = __builtin_amdgcn_mfma_f32_16x16x32_bf16(kfh, qfh, c, 0, 0, 0);
      c = __builtin_amdgcn_mfma_f32_16x16x32_bf16(kfh, qfl, c, 0, 0, 0);
      c = __builtin_amdgcn_mfma_f32_16x16x32_bf16(kfl, qfh, c, 0, 0, 0);
      s[t] = c;
    }

    // ---- online softmax (base-2 domain)
    float mx = s[0][0];
    #pragma unroll
    for (int t = 0; t < 8; ++t)
      #pragma unroll
      for (int r = 0; r < 4; ++r) mx = fmaxf(mx, s[t][r]);
    mx = fmaxf(mx, __shfl_xor(mx, 16));
    mx = fmaxf(mx, __shfl_xor(mx, 32));
    float mn = fmaxf(m, mx);
    float corr = __builtin_amdgcn_exp2f(m - mn);
    m = mn;

    float ls = 0.f;
    #pragma unroll
    for (int t = 0; t < 8; ++t) {
      #pragma unroll
      for (int r = 0; r < 4; ++r) {
        s[t][r] = __builtin_amdgcn_exp2f(s[t][r] - mn);
        ls += s[t][r];
      }
    }
    ls += __shfl_xor(ls, 16);
    ls += __shfl_xor(ls, 32);
    lr = lr * corr + ls;
    #pragma unroll
    for (int r = 0; r < 4; ++r) O[r] *= corr;

    // ---- P -> bf16 (RNE), explicit placement in LDS: P_lds[wid][q][key]
    #pragma unroll
    for (int t = 0; t < 8; ++t) {
      unsigned p01 = bf16rne(s[t][0]) | (bf16rne(s[t][1]) << 16);
      unsigned p23 = bf16rne(s[t][2]) | (bf16rne(s[t][3]) << 16);
      *(unsigned*)&P_lds[wid][q][t * 16 + g * 4 + 0] = p01;
      *(unsigned*)&P_lds[wid][q][t * 16 + g * 4 + 2] = p23;
    }
    asm volatile("s_waitcnt lgkmcnt(0)" ::: "memory");

    // ---- PV: O^T += V^T . P^T  (B-frag = 8 consecutive keys from LDS)
    #pragma unroll
    for (int km = 0; km < 4; ++km) {
      s16x8 pfrag = *(const s16x8*)&P_lds[wid][q][km * 32 + g * 8];
      s16x8 vf = {0,0,0,0,0,0,0,0};
      if (q < 8)
        vf = *(const s16x8*)(vbase + (size_t)q * HW_ + bk * 128 + km * 32 + g * 8);
      O = __builtin_amdgcn_mfma_f32_16x16x32_bf16(vf, pfrag, O, 0, 0, 0);
    }
  }

  // ---- epilogue: O^T rows d = g*4+r, col q; normalize and store fp32
  if (g < 2) {
    float inv = 1.f / lr;
    int qrow = qt * 64 + wid * 16 + q;
    float* ap = aws + ((size_t)b * 64 + n * 8) * HW_;
    #pragma unroll
    for (int r = 0; r < 4; ++r)
      ap[(size_t)(g * 4 + r) * HW_ + qrow] = O[r] * inv;
  }
}

// ---------------- K3: 1x1 conv on attention map ----------------
// grid 256 = b(4) x ocq(16) x pt(4); 256 thr = 4 oc x 64 p-quads
__global__ __launch_bounds__(256) void k_attnconv(
    const float* __restrict__ aws, const float* __restrict__ w_attn, const float* __restrict__ b_attn,
    float* __restrict__ out)
{
  int bid = blockIdx.x;
  int pt  = bid & 3;
  int ocq = (bid >> 2) & 15;
  int b   = bid >> 6;
  int tid = threadIdx.x;
  int oc  = ocq * 4 + (tid >> 6);
  int p   = pt * 256 + (tid & 63) * 4;

  const float* wrow = w_attn + oc * 64;
  float bias = b_attn[oc];
  float4 acc = make_float4(bias, bias, bias, bias);
  const float* ab = aws + (size_t)b * 64 * HW_ + p;
  #pragma unroll 16
  for (int ci = 0; ci < 64; ++ci) {
    float wv = wrow[ci];
    float4 a4 = *(const float4*)(ab + (size_t)ci * HW_);
    acc.x = fmaf(wv, a4.x, acc.x);
    acc.y = fmaf(wv, a4.y, acc.y);
    acc.z = fmaf(wv, a4.z, acc.z);
    acc.w = fmaf(wv, a4.w, acc.w);
  }
  *(float4*)(out + ((size_t)b * 128 + 64 + oc) * HW_ + p) = acc;
}

extern "C" void kernel_launch(void* const* d_in, const int* in_sizes, int n_in,
                              void* d_out, int out_size, void* d_ws, size_t ws_size,
                              hipStream_t stream) {
  const float* x        = (const float*)d_in[0];
  const float* w_conv   = (const float*)d_in[1];
  const float* b_conv   = (const float*)d_in[2];
  const float* w_qkv    = (const float*)d_in[3];
  const float* b_qkv    = (const float*)d_in[4];
  const float* w_attn   = (const float*)d_in[5];
  const float* b_attn   = (const float*)d_in[6];
  const float* rel_h    = (const float*)d_in[7];
  const float* rel_w    = (const float*)d_in[8];
  float* out = (float*)d_out;

  float*  ws  = (float*)d_ws;
  float*  aws = ws;                               // [4][64][1024] f32 (1MB)
  ushort* qh  = (ushort*)(ws + 262144);           // [32][1024][8] bf16 x5 (2.5MB)
  ushort* ql  = qh + 262144;
  ushort* kh  = ql + 262144;
  ushort* kl  = kh + 262144;
  ushort* vtg = kl + 262144;

  k_convs<<<1024, 256, 0, stream>>>(x, w_conv, b_conv, w_qkv, b_qkv, out, qh, ql, kh, kl, vtg);
  k_attn<<<512, 256, 0, stream>>>(qh, ql, kh, kl, vtg, rel_h, rel_w, aws);
  k_attnconv<<<256, 256, 0, stream>>>(aws, w_attn, b_attn, out);
}

// Round 6
// 50.858 us; speedup vs baseline: 5.5701x; 1.3447x over previous
//
#include <hip/hip_runtime.h>
#include <math.h>

#define HW_ 1024

typedef __attribute__((ext_vector_type(4))) float   f32x4;
typedef __attribute__((ext_vector_type(8))) short   s16x8;

__device__ __forceinline__ unsigned bf16rne(float x) {
  unsigned u = __builtin_bit_cast(unsigned, x);
  u += 0x7FFF + ((u >> 16) & 1);
  return u >> 16;
}

// ---------------- K1: fused 1x1 convs (conv_out + q/k/v staging, bf16) ----------------
// grid 1024 = b(4) x ocq(64) x pt(4); 256 thr = 4 oc x 64 p-quads
__global__ __launch_bounds__(256) void k_convs(
    const float* __restrict__ x, const float* __restrict__ w_conv, const float* __restrict__ b_conv,
    const float* __restrict__ w_qkv, const float* __restrict__ b_qkv,
    float* __restrict__ out,
    ushort* __restrict__ qbf, ushort* __restrict__ kbf, ushort* __restrict__ vtg)
{
  int bid = blockIdx.x;
  int pt  = bid & 3;
  int ocq = (bid >> 2) & 63;
  int b   = bid >> 8;
  int tid = threadIdx.x;
  int oc  = ocq * 4 + (tid >> 6);          // 0..255 (wave-uniform)
  int p   = pt * 256 + (tid & 63) * 4;

  const float* wrow;
  float bias;
  if (oc < 64) { wrow = w_conv + oc * 64; bias = b_conv[oc]; }
  else         { wrow = w_qkv + (oc - 64) * 64; bias = b_qkv[oc - 64]; }

  float4 acc = make_float4(bias, bias, bias, bias);
  const float* xb = x + (size_t)b * 64 * HW_ + p;
  #pragma unroll 16
  for (int ci = 0; ci < 64; ++ci) {
    float wv = wrow[ci];
    float4 x4 = *(const float4*)(xb + (size_t)ci * HW_);
    acc.x = fmaf(wv, x4.x, acc.x);
    acc.y = fmaf(wv, x4.y, acc.y);
    acc.z = fmaf(wv, x4.z, acc.z);
    acc.w = fmaf(wv, x4.w, acc.w);
  }

  float av[4] = {acc.x, acc.y, acc.z, acc.w};
  if (oc < 64) {
    *(float4*)(out + ((size_t)b * 128 + oc) * HW_ + p) = acc;
  } else if (oc < 128) {
    // q: scale by dkh^-0.5 * log2(e) (exp2 domain), bf16, layout [bn][p][8]
    const float SC = 0.35355339059327373f * 1.4426950408889634f;
    int qc = oc - 64, n = qc >> 3, d = qc & 7, bn = b * 8 + n;
    #pragma unroll
    for (int i = 0; i < 4; ++i)
      qbf[((size_t)bn * HW_ + p + i) * 8 + d] = (ushort)bf16rne(av[i] * SC);
  } else if (oc < 192) {
    int kc = oc - 128, n = kc >> 3, d = kc & 7, bn = b * 8 + n;
    #pragma unroll
    for (int i = 0; i < 4; ++i)
      kbf[((size_t)bn * HW_ + p + i) * 8 + d] = (ushort)bf16rne(av[i]);
  } else {
    // v transposed: [bn][d][p]
    int vc = oc - 192, n = vc >> 3, d = vc & 7, bn = b * 8 + n;
    #pragma unroll
    for (int i = 0; i < 4; ++i)
      vtg[((size_t)bn * 8 + d) * HW_ + p + i] = (ushort)bf16rne(av[i]);
  }
}

// ---------------- K2: MFMA flash attention, key-split 2-way ----------------
// grid 512 = bn(32) x qt(16); 512 thr = 8 waves: qsub(4) x key-half(2)
// wave: 16 q-cols x 512 keys. S^T = mfma(K, Q^T, C=rel); P via per-wave
// swizzled LDS; O^T = mfma(V^T(+ones row), P^T, O); l rides in O row d=8.
__global__ __launch_bounds__(512, 4) void k_attn(
    const ushort* __restrict__ qbf, const ushort* __restrict__ kbf, const ushort* __restrict__ vtg,
    const float* __restrict__ rel_h, const float* __restrict__ rel_w,
    float* __restrict__ aws)
{
  __shared__ float rhd[64 * 33];
  __shared__ float rwd[64 * 33];
  __shared__ ushort P_lds[8][16][128];   // per-wave [q][key], 256B rows, XOR-swizzled
  __shared__ float mbuf[4][16], lbuf[4][16];
  __shared__ float obuf[4][16][8];

  int bid = blockIdx.x;
  int qt = bid & 15;
  int bn = bid >> 4;
  int b = bn >> 3, n = bn & 7;
  int tid = threadIdx.x;
  int lane = tid & 63;
  int w = tid >> 6;
  int qsub = w & 3, half = w >> 2;

  // ---- build rel tables: rhd[qr][hp] = q.rel_h[hp-h+31], rwd[qr][wp] = q.rel_w[wp-w+31]
  {
    int qr = tid >> 3, qu = tid & 7;
    const ushort* qp = qbf + ((size_t)bn * HW_ + qt * 64 + qr) * 8;
    float qf[8];
    #pragma unroll
    for (int d = 0; d < 8; ++d) qf[d] = __builtin_bit_cast(float, (unsigned)qp[d] << 16);
    int h = (qt * 64 + qr) >> 5, ww = qr & 31;
    #pragma unroll
    for (int s = 0; s < 4; ++s) {
      int idx = qu * 4 + s;
      const float* rp = rel_h + (idx - h + 31) * 8;
      float a = 0.f;
      #pragma unroll
      for (int d = 0; d < 8; ++d) a = fmaf(qf[d], rp[d], a);
      rhd[qr * 33 + idx] = a;
      const float* rq = rel_w + (idx - ww + 31) * 8;
      float c = 0.f;
      #pragma unroll
      for (int d = 0; d < 8; ++d) c = fmaf(qf[d], rq[d], c);
      rwd[qr * 33 + idx] = c;
    }
  }
  __syncthreads();

  int q = lane & 15, g = lane >> 4;
  int qr = qsub * 16 + q;

  s16x8 qfrag = {0,0,0,0,0,0,0,0};
  if (lane < 16)
    qfrag = *(const s16x8*)(qbf + ((size_t)bn * HW_ + qt * 64 + qsub * 16 + lane) * 8);

  float rw2[2][4];
  #pragma unroll
  for (int r = 0; r < 4; ++r) {
    rw2[0][r] = rwd[qr * 33 + g * 4 + r];
    rw2[1][r] = rwd[qr * 33 + 16 + g * 4 + r];
  }

  const ushort* kbase = kbf + (size_t)bn * HW_ * 8;
  const ushort* vbase = vtg + (size_t)bn * 8 * HW_;

  s16x8 vone;
  #pragma unroll
  for (int e = 0; e < 8; ++e) vone[e] = (short)0x3F80;   // bf16 1.0
  s16x8 vzero = {0,0,0,0,0,0,0,0};

  float m = -1e30f;
  f32x4 O = {0.f, 0.f, 0.f, 0.f};

  char* prow = (char*)&P_lds[w][0][0] + q * 256;
  int sw = (q & 7) << 4;

  #pragma unroll
  for (int bki = 0; bki < 4; ++bki) {
    int bk = half * 4 + bki;
    float rh4[4];
    #pragma unroll
    for (int j = 0; j < 4; ++j) rh4[j] = rhd[qr * 33 + bk * 4 + j];

    // ---- QK^T (S^T), rel logits as C-init
    f32x4 s[8];
    #pragma unroll
    for (int t = 0; t < 8; ++t) {
      f32x4 c;
      #pragma unroll
      for (int r = 0; r < 4; ++r) c[r] = rh4[t >> 1] + rw2[t & 1][r];
      s16x8 kf = {0,0,0,0,0,0,0,0};
      if (lane < 16)
        kf = *(const s16x8*)(kbase + (size_t)(bk * 128 + t * 16 + lane) * 8);
      s[t] = __builtin_amdgcn_mfma_f32_16x16x32_bf16(kf, qfrag, c, 0, 0, 0);
    }

    // ---- online softmax max (base-2 domain)
    float t8[8];
    #pragma unroll
    for (int t = 0; t < 8; ++t)
      t8[t] = fmaxf(fmaxf(s[t][0], s[t][1]), fmaxf(s[t][2], s[t][3]));
    float mx = fmaxf(fmaxf(fmaxf(t8[0], t8[1]), fmaxf(t8[2], t8[3])),
                     fmaxf(fmaxf(t8[4], t8[5]), fmaxf(t8[6], t8[7])));
    mx = fmaxf(mx, __shfl_xor(mx, 16));
    mx = fmaxf(mx, __shfl_xor(mx, 32));
    float mn = fmaxf(m, mx);
    float corr = __builtin_amdgcn_exp2f(m - mn);
    m = mn;

    #pragma unroll
    for (int t = 0; t < 8; ++t)
      #pragma unroll
      for (int r = 0; r < 4; ++r)
        s[t][r] = __builtin_amdgcn_exp2f(s[t][r] - mn);

    #pragma unroll
    for (int r = 0; r < 4; ++r) O[r] *= corr;

    // ---- pack P (RNE via cvt_pk) into swizzled per-wave LDS
    #pragma unroll
    for (int t = 0; t < 8; ++t) {
      unsigned w0, w1;
      asm("v_cvt_pk_bf16_f32 %0, %1, %2" : "=v"(w0) : "v"(s[t][0]), "v"(s[t][1]));
      asm("v_cvt_pk_bf16_f32 %0, %1, %2" : "=v"(w1) : "v"(s[t][2]), "v"(s[t][3]));
      *(uint2*)(prow + (((t * 32 + g * 8) ^ sw))) = make_uint2(w0, w1);
    }
    asm volatile("s_waitcnt lgkmcnt(0)" ::: "memory");

    // ---- PV: O^T += [V^T; ones] . P^T
    #pragma unroll
    for (int km = 0; km < 4; ++km) {
      s16x8 pfrag = *(const s16x8*)(prow + ((km * 64 + g * 16) ^ sw));
      s16x8 vf;
      if (q < 8)      vf = *(const s16x8*)(vbase + (size_t)q * HW_ + bk * 128 + km * 32 + g * 8);
      else if (q == 8) vf = vone;
      else             vf = vzero;
      O = __builtin_amdgcn_mfma_f32_16x16x32_bf16(vf, pfrag, O, 0, 0, 0);
    }
  }

  // l = row d=8 of O^T (lane 32+q, reg 0), broadcast to all lanes
  float l = __shfl(O[0], 32 + q);

  // ---- merge the two key-halves via LDS
  if (half == 1) {
    if (g < 2) {
      #pragma unroll
      for (int r = 0; r < 4; ++r) obuf[qsub][q][g * 4 + r] = O[r];
    }
    if (lane < 16) { mbuf[qsub][lane] = m; lbuf[qsub][lane] = l; }
  }
  __syncthreads();
  if (half == 0 && g < 2) {
    float m2 = mbuf[qsub][q], l2 = lbuf[qsub][q];
    float mn = fmaxf(m, m2);
    float c1 = __builtin_amdgcn_exp2f(m - mn);
    float c2 = __builtin_amdgcn_exp2f(m2 - mn);
    float inv = 1.f / (l * c1 + l2 * c2);
    int qrow = qt * 64 + qsub * 16 + q;
    float* ap = aws + ((size_t)b * 64 + n * 8) * HW_;
    #pragma unroll
    for (int r = 0; r < 4; ++r)
      ap[(size_t)(g * 4 + r) * HW_ + qrow] = (O[r] * c1 + obuf[qsub][q][g * 4 + r] * c2) * inv;
  }
}

// ---------------- K3: 1x1 conv on attention map ----------------
// grid 256 = b(4) x ocq(16) x pt(4); 256 thr = 4 oc x 64 p-quads
__global__ __launch_bounds__(256) void k_attnconv(
    const float* __restrict__ aws, const float* __restrict__ w_attn, const float* __restrict__ b_attn,
    float* __restrict__ out)
{
  int bid = blockIdx.x;
  int pt  = bid & 3;
  int ocq = (bid >> 2) & 15;
  int b   = bid >> 6;
  int tid = threadIdx.x;
  int oc  = ocq * 4 + (tid >> 6);
  int p   = pt * 256 + (tid & 63) * 4;

  const float* wrow = w_attn + oc * 64;
  float bias = b_attn[oc];
  float4 acc = make_float4(bias, bias, bias, bias);
  const float* ab = aws + (size_t)b * 64 * HW_ + p;
  #pragma unroll 16
  for (int ci = 0; ci < 64; ++ci) {
    float wv = wrow[ci];
    float4 a4 = *(const float4*)(ab + (size_t)ci * HW_);
    acc.x = fmaf(wv, a4.x, acc.x);
    acc.y = fmaf(wv, a4.y, acc.y);
    acc.z = fmaf(wv, a4.z, acc.z);
    acc.w = fmaf(wv, a4.w, acc.w);
  }
  *(float4*)(out + ((size_t)b * 128 + 64 + oc) * HW_ + p) = acc;
}

extern "C" void kernel_launch(void* const* d_in, const int* in_sizes, int n_in,
                              void* d_out, int out_size, void* d_ws, size_t ws_size,
                              hipStream_t stream) {
  const float* x        = (const float*)d_in[0];
  const float* w_conv   = (const float*)d_in[1];
  const float* b_conv   = (const float*)d_in[2];
  const float* w_qkv    = (const float*)d_in[3];
  const float* b_qkv    = (const float*)d_in[4];
  const float* w_attn   = (const float*)d_in[5];
  const float* b_attn   = (const float*)d_in[6];
  const float* rel_h    = (const float*)d_in[7];
  const float* rel_w    = (const float*)d_in[8];
  float* out = (float*)d_out;

  float*  ws  = (float*)d_ws;
  float*  aws = ws;                               // [4][64][1024] f32 (1MB)
  ushort* qbf = (ushort*)(ws + 262144);           // [32][1024][8] bf16 (512KB)
  ushort* kbf = qbf + 262144;                     // [32][1024][8] bf16 (512KB)
  ushort* vtg = kbf + 262144;                     // [32][8][1024] bf16 (512KB)

  k_convs<<<1024, 256, 0, stream>>>(x, w_conv, b_conv, w_qkv, b_qkv, out, qbf, kbf, vtg);
  k_attn<<<512, 512, 0, stream>>>(qbf, kbf, vtg, rel_h, rel_w, aws);
  k_attnconv<<<256, 256, 0, stream>>>(aws, w_attn, b_attn, out);
}